// Round 6
// baseline (192.642 us; speedup 1.0000x reference)
//
#include <hip/hip_runtime.h>
#include <hip/hip_bf16.h>

#define T_TOK 2048
#define H_DIM 1024
#define E_NUM 16
#define I_DIM 512
#define K_TOP 4
#define SI_DIM 1024

typedef __bf16 bf16x8 __attribute__((ext_vector_type(8)));
typedef __bf16 bf16x4 __attribute__((ext_vector_type(4)));
typedef __bf16 bf16x2 __attribute__((ext_vector_type(2)));
typedef float f32x4 __attribute__((ext_vector_type(4)));

#define GL2L(g, l)                                                                       \
  __builtin_amdgcn_global_load_lds((const __attribute__((address_space(1))) void*)(g),   \
                                   (__attribute__((address_space(3))) void*)(l), 16, 0, 0)

// ---------------- transpose gate_weight [H,E] -> [E,H] (tiny) ----------------
__global__ void transpose_gw_kernel(const float* __restrict__ in, float* __restrict__ out) {
  int idx = blockIdx.x * 256 + threadIdx.x;  // 16384
  int e = idx >> 10, h = idx & 1023;
  out[idx] = in[h * E_NUM + e];
}

// -------- ALL weight transposes in one launch: fp32 [Z,R,C] -> bf16 [Z,C,R] --------
// 64-row x 32-col tiles; packed bf16x2 stores (4B/lane, 128B/wave contiguous).
// segments: [0,4096) gw, [4096,8192) uw, [8192,12288) dw, then sgw/suw/sdw 512 each.
__global__ void transpose_all_kernel(const float* __restrict__ gate_w,
                                     const float* __restrict__ up_w,
                                     const float* __restrict__ down_w,
                                     const float* __restrict__ sgw, const float* __restrict__ suw,
                                     const float* __restrict__ sdw, __bf16* __restrict__ gw_t,
                                     __bf16* __restrict__ uw_t, __bf16* __restrict__ dw_t,
                                     __bf16* __restrict__ sgw_t, __bf16* __restrict__ suw_t,
                                     __bf16* __restrict__ sdw_t) {
  __shared__ float tile[64][33];
  int bid = blockIdx.x;
  const float* in;
  __bf16* out;
  int R, C, tile_id;
  if (bid < 8192) {
    bool g = bid < 4096;
    int b = bid & 4095;
    int z = b >> 8;
    tile_id = b & 255;
    R = H_DIM;
    C = I_DIM;
    size_t off = (size_t)z * R * C;
    in = (g ? gate_w : up_w) + off;
    out = (g ? gw_t : uw_t) + off;
  } else if (bid < 12288) {
    int b = bid - 8192;
    int z = b >> 8;
    tile_id = b & 255;
    R = I_DIM;
    C = H_DIM;
    size_t off = (size_t)z * R * C;
    in = down_w + off;
    out = dw_t + off;
  } else {
    int b = bid - 12288;
    int m = b >> 9;
    tile_id = b & 511;
    R = SI_DIM;
    C = H_DIM;
    in = m == 0 ? sgw : m == 1 ? suw : sdw;
    out = m == 0 ? sgw_t : m == 1 ? suw_t : sdw_t;
  }
  int xt = C >> 5;
  int cx = tile_id % xt, ry = tile_id / xt;
  int c0 = cx * 32, r0 = ry * 64;
  int tx = threadIdx.x, ty = threadIdx.y;  // 32 x 8
#pragma unroll
  for (int j = 0; j < 8; j++)
    tile[ty + 8 * j][tx] = in[(size_t)(r0 + ty + 8 * j) * C + c0 + tx];
  __syncthreads();
#pragma unroll
  for (int j = 0; j < 4; j++) {
    int cc = ty + 8 * j;
    bf16x2 v = {(__bf16)tile[tx * 2][cc], (__bf16)tile[tx * 2 + 1][cc]};
    *(bf16x2*)(out + (size_t)(c0 + cc) * R + r0 + tx * 2) = v;
  }
}

// ---------------- router: one block (4 waves) per token, fused x->bf16 cast ----------
__global__ __launch_bounds__(256) void router_kernel(
    const float* __restrict__ x, const float* __restrict__ gwt, const float* __restrict__ cbias,
    float* __restrict__ logits_out, __bf16* __restrict__ x_bf, int* __restrict__ selE,
    float* __restrict__ selW) {
  int t = blockIdx.x;
  int tid = threadIdx.x;
  int wid = tid >> 6, lane = tid & 63;
  int e = lane >> 2, cl = lane & 3;
  int c = wid * 4 + cl;  // 0..15
  const float* xr = x + (size_t)t * H_DIM + c * 64;
  const float* gr = gwt + (size_t)e * H_DIM + c * 64;
  float a0 = 0.f, a1 = 0.f, a2 = 0.f, a3 = 0.f;
#pragma unroll
  for (int j = 0; j < 16; j++) {
    float4 xv = *(const float4*)(xr + j * 4);
    float4 gv = *(const float4*)(gr + j * 4);
    if (e == 0) {
      bf16x4 o = {(__bf16)xv.x, (__bf16)xv.y, (__bf16)xv.z, (__bf16)xv.w};
      *(bf16x4*)(x_bf + (size_t)t * H_DIM + c * 64 + j * 4) = o;
    }
    a0 = fmaf(xv.x, gv.x, a0);
    a1 = fmaf(xv.y, gv.y, a1);
    a2 = fmaf(xv.z, gv.z, a2);
    a3 = fmaf(xv.w, gv.w, a3);
  }
  float a = (a0 + a1) + (a2 + a3);
  a += __shfl_xor(a, 1);
  a += __shfl_xor(a, 2);
  __shared__ float part[4][16];
  if (cl == 0) part[wid][e] = a;
  __syncthreads();
  if (wid != 0) return;
  float logit = -1e30f;
  if (lane < E_NUM)
    logit = (part[0][lane] + part[1][lane]) + (part[2][lane] + part[3][lane]);
  if (lane < E_NUM) logits_out[(size_t)t * E_NUM + lane] = logit;
  float m = logit;
#pragma unroll
  for (int mk = 8; mk >= 1; mk >>= 1) m = fmaxf(m, __shfl_xor(m, mk));
  float p = __expf(logit - m);
  float s = p;
#pragma unroll
  for (int mk = 8; mk >= 1; mk >>= 1) s += __shfl_xor(s, mk);
  p /= s;
  float score = (lane < E_NUM) ? p + cbias[lane] : -1e30f;
  int sel[K_TOP];
  float w[K_TOP];
#pragma unroll
  for (int k = 0; k < K_TOP; k++) {
    float bv = score;
    int bi = (lane < E_NUM) ? lane : 999;
#pragma unroll
    for (int mk = 1; mk <= 8; mk <<= 1) {
      float ov = __shfl_xor(bv, mk);
      int oi = __shfl_xor(bi, mk);
      if (ov > bv || (ov == bv && oi < bi)) {
        bv = ov;
        bi = oi;
      }
    }
    sel[k] = bi;
    w[k] = __shfl(p, bi);
    if (lane == bi) score = -1e30f;
  }
  if (lane == 0) {
    float wsum = fmaxf(w[0] + w[1] + w[2] + w[3], 1e-12f);
#pragma unroll
    for (int k = 0; k < K_TOP; k++) {
      selE[t * K_TOP + k] = sel[k];
      selW[t * K_TOP + k] = w[k] / wsum;
    }
  }
}

// ---------------- count + place, ONE block, ballot-based, zero global atomics ----------
__global__ __launch_bounds__(1024) void count_place_kernel(
    const int* __restrict__ selE, int* __restrict__ counts, int* __restrict__ offs,
    int* __restrict__ slot_of_tk, int* __restrict__ tok_of_slot) {
  int tid = threadIdx.x;
  int wv = tid >> 6, lane = tid & 63;
  unsigned long long lt = (1ULL << lane) - 1ULL;
  __shared__ int wcnt[16][16];
  __shared__ int wbase[16][16];
  __shared__ int glob[16];
  __shared__ int offsh[16];
  if (tid < 16) glob[tid] = 0;
  __syncthreads();
  int ex[8], rk[8];
#pragma unroll
  for (int r = 0; r < 8; r++) {
    int e = selE[r * 1024 + tid];
    ex[r] = e;
    int rank = 0;
#pragma unroll
    for (int q = 0; q < 16; q++) {
      unsigned long long b = __ballot(e == q);
      int c = __popcll(b & lt);
      if (e == q) rank = c;
      if (lane == q) wcnt[wv][q] = __popcll(b);
    }
    __syncthreads();
    if (wv == 0 && lane < 16) {
      int run = glob[lane];
#pragma unroll
      for (int w = 0; w < 16; w++) {
        wbase[w][lane] = run;
        run += wcnt[w][lane];
      }
      glob[lane] = run;
    }
    __syncthreads();
    rk[r] = rank + wbase[wv][e];
    __syncthreads();
  }
  if (wv == 0 && lane == 0) {
    int s = 0;
#pragma unroll
    for (int q = 0; q < 16; q++) {
      offsh[q] = s;
      s += glob[q];
    }
  }
  __syncthreads();
  if (tid < 16) {
    counts[tid] = glob[tid];
    offs[tid] = offsh[tid];
  }
#pragma unroll
  for (int r = 0; r < 8; r++) {
    int entry = r * 1024 + tid;
    int slot = offsh[ex[r]] + rk[r];
    slot_of_tk[entry] = slot;
    tok_of_slot[slot] = entry >> 2;
  }
}

// ---- 128x128 tile, BK=64, XOR-swizzled LDS, 2-phase double-buffered pipeline ----
// GL2L writes linearly; source chunk pre-swizzled (chunk^rsub), read chunk (q^xa):
// same involution both sides (rule #21). Pipeline: stage(next) || ds_read+MFMA(cur),
// counted drains with RAW s_barrier (no __syncthreads: it would emit vmcnt(0) drains).
__device__ __forceinline__ void gemm_tile(const __bf16* __restrict__ A,
                                          const int* __restrict__ tokIdx, int rowOff, int M,
                                          int m0, int n0, int K, int ldC,
                                          const __bf16* __restrict__ Bp, __bf16* __restrict__ Cp,
                                          __bf16* Alds, __bf16* Blds) {
  int tid = threadIdx.x;
  int wave = tid >> 6, lane = tid & 63;
  int rsub = lane >> 3, chunk = lane & 7;
  int sch = (chunk ^ rsub) * 8;  // swizzled source offset (elems)
  size_t aB[4], bB[4];
#pragma unroll
  for (int j = 0; j < 4; j++) {
    int r = wave * 32 + j * 8 + rsub;
    int ar = m0 + r;
    ar = ar < M - 1 ? ar : M - 1;
    int grow = tokIdx ? tokIdx[rowOff + ar] : rowOff + ar;
    aB[j] = (size_t)grow * K + sch;
    bB[j] = (size_t)(n0 + r) * K + sch;
  }
  int wm = (wave >> 1) * 64, wn = (wave & 1) * 64;
  int rl = lane & 15, gq = lane >> 4;
  int xa = rl & 7;

  auto STAGE = [&](int buf, int k0) {
    __bf16* Ad = Alds + buf * 8192;
    __bf16* Bd = Blds + buf * 8192;
#pragma unroll
    for (int j = 0; j < 4; j++) {
      GL2L(A + aB[j] + k0, Ad + (wave * 32 + j * 8) * 64);
      GL2L(Bp + bB[j] + k0, Bd + (wave * 32 + j * 8) * 64);
    }
  };

  f32x4 acc[4][4] = {};
  const int NT = K >> 6;
  STAGE(0, 0);
  asm volatile("s_waitcnt vmcnt(0)" ::: "memory");
  __builtin_amdgcn_s_barrier();
  int cur = 0;
  for (int t = 0; t < NT; ++t) {
    if (t + 1 < NT) STAGE(cur ^ 1, (t + 1) << 6);
    const __bf16* Ar = Alds + cur * 8192;
    const __bf16* Br = Blds + cur * 8192;
    bf16x8 af[2][4], bfr[2][4];
#pragma unroll
    for (int s = 0; s < 2; s++) {
      int lc = ((s * 4 + gq) ^ xa) * 8;
#pragma unroll
      for (int m = 0; m < 4; m++) af[s][m] = *(const bf16x8*)&Ar[(wm + m * 16 + rl) * 64 + lc];
#pragma unroll
      for (int n = 0; n < 4; n++) bfr[s][n] = *(const bf16x8*)&Br[(wn + n * 16 + rl) * 64 + lc];
    }
    asm volatile("s_waitcnt lgkmcnt(0)" ::: "memory");
    __builtin_amdgcn_sched_barrier(0);
#pragma unroll
    for (int s = 0; s < 2; s++)
#pragma unroll
      for (int m = 0; m < 4; m++)
#pragma unroll
        for (int n = 0; n < 4; n++)
          acc[m][n] =
              __builtin_amdgcn_mfma_f32_16x16x32_bf16(af[s][m], bfr[s][n], acc[m][n], 0, 0, 0);
    if (t + 1 < NT) {
      asm volatile("s_waitcnt vmcnt(0)" ::: "memory");
      __builtin_amdgcn_s_barrier();
    }
    cur ^= 1;
  }
#pragma unroll
  for (int m = 0; m < 4; m++) {
#pragma unroll
    for (int b = 0; b < 4; b++) {
      int row = m0 + wm + m * 16 + gq * 4 + b;
      if (row < M) {
        size_t rb = (size_t)(rowOff + row) * ldC + n0 + wn + rl;
#pragma unroll
        for (int n = 0; n < 4; n++) Cp[rb + n * 16] = (__bf16)acc[m][n][b];
      }
    }
  }
}

// stage 1: expert gate+up (z<16, gathered A) + shared gate+up (z==16, identity A)
__global__ __launch_bounds__(256, 2) void gemm_stage1(
    const __bf16* __restrict__ x_bf, const int* __restrict__ tok_of_slot,
    const int* __restrict__ counts, const int* __restrict__ offs, const __bf16* __restrict__ gw_t,
    const __bf16* __restrict__ uw_t, const __bf16* __restrict__ sgw_t,
    const __bf16* __restrict__ suw_t, __bf16* __restrict__ g_buf, __bf16* __restrict__ u_buf,
    __bf16* __restrict__ gs_buf, __bf16* __restrict__ us_buf) {
  __shared__ __align__(16) __bf16 Alds[2 * 8192];
  __shared__ __align__(16) __bf16 Blds[2 * 8192];
  int z = blockIdx.z, bx = blockIdx.x, m0 = blockIdx.y * 128;
  if (z < E_NUM) {
    if (bx >= 8) return;
    int M = counts[z];
    if (m0 >= M) return;
    bool gate = bx < 4;
    const __bf16* Bp = (gate ? gw_t : uw_t) + (size_t)z * I_DIM * H_DIM;
    __bf16* Cp = gate ? g_buf : u_buf;
    gemm_tile(x_bf, tok_of_slot, offs[z], M, m0, (bx & 3) * 128, H_DIM, I_DIM, Bp, Cp, Alds,
              Blds);
  } else {
    bool gate = bx < 8;
    const __bf16* Bp = gate ? sgw_t : suw_t;
    __bf16* Cp = gate ? gs_buf : us_buf;
    gemm_tile(x_bf, nullptr, 0, T_TOK, m0, (bx & 7) * 128, H_DIM, SI_DIM, Bp, Cp, Alds, Blds);
  }
}

// stage 2: expert down (z<16) + shared down (z==16)
__global__ __launch_bounds__(256, 2) void gemm_stage2(
    const __bf16* __restrict__ he, const __bf16* __restrict__ hs, const int* __restrict__ counts,
    const int* __restrict__ offs, const __bf16* __restrict__ dw_t,
    const __bf16* __restrict__ sdw_t, __bf16* __restrict__ eo, __bf16* __restrict__ so) {
  __shared__ __align__(16) __bf16 Alds[2 * 8192];
  __shared__ __align__(16) __bf16 Blds[2 * 8192];
  int z = blockIdx.z, bx = blockIdx.x, m0 = blockIdx.y * 128;
  if (z < E_NUM) {
    int M = counts[z];
    if (m0 >= M) return;
    gemm_tile(he, nullptr, offs[z], M, m0, bx * 128, I_DIM, H_DIM,
              dw_t + (size_t)z * H_DIM * I_DIM, eo, Alds, Blds);
  } else {
    gemm_tile(hs, nullptr, 0, T_TOK, m0, bx * 128, SI_DIM, H_DIM, sdw_t, so, Alds, Blds);
  }
}

// ---------------- silu(g)*u elementwise (expert + shared merged) ----------------
__global__ void silu_mul_kernel(const __bf16* __restrict__ g, const __bf16* __restrict__ u,
                                __bf16* __restrict__ h, long n8) {
  long i = blockIdx.x * (long)blockDim.x + threadIdx.x;
  if (i >= n8) return;
  bf16x8 gv = *(const bf16x8*)(g + i * 8);
  bf16x8 uv = *(const bf16x8*)(u + i * 8);
  bf16x8 hv;
#pragma unroll
  for (int j = 0; j < 8; j++) {
    float gf = (float)gv[j];
    float s = gf / (1.f + __expf(-gf));
    hv[j] = (__bf16)(s * (float)uv[j]);
  }
  *(bf16x8*)(h + i * 8) = hv;
}

// ---------------- combine: out = shared + sum_k w_k * eo[slot_k] ----------------
__global__ void combine_kernel(const __bf16* __restrict__ eo, const __bf16* __restrict__ so,
                               const int* __restrict__ slot_of_tk, const float* __restrict__ selW,
                               float* __restrict__ out) {
  int idx = blockIdx.x * blockDim.x + threadIdx.x;
  int t = idx >> 8;
  int h4 = (idx & 255) * 4;
  if (t >= T_TOK) return;
  bf16x4 sv = *(const bf16x4*)(so + (size_t)t * H_DIM + h4);
  float a0 = (float)sv[0], a1 = (float)sv[1], a2 = (float)sv[2], a3 = (float)sv[3];
#pragma unroll
  for (int k = 0; k < K_TOP; k++) {
    int slot = slot_of_tk[t * K_TOP + k];
    float w = selW[t * K_TOP + k];
    bf16x4 ev = *(const bf16x4*)(eo + (size_t)slot * H_DIM + h4);
    a0 += w * (float)ev[0];
    a1 += w * (float)ev[1];
    a2 += w * (float)ev[2];
    a3 += w * (float)ev[3];
  }
  *(float4*)(out + (size_t)t * H_DIM + h4) = make_float4(a0, a1, a2, a3);
}

extern "C" void kernel_launch(void* const* d_in, const int* in_sizes, int n_in, void* d_out,
                              int out_size, void* d_ws, size_t ws_size, hipStream_t stream) {
  const float* x = (const float*)d_in[0];
  const float* gate_weight = (const float*)d_in[1];
  const float* corr_bias = (const float*)d_in[2];
  const float* gate_w = (const float*)d_in[3];
  const float* up_w = (const float*)d_in[4];
  const float* down_w = (const float*)d_in[5];
  const float* sgw = (const float*)d_in[6];
  const float* suw = (const float*)d_in[7];
  const float* sdw = (const float*)d_in[8];
  float* out = (float*)d_out;
  float* logits_out = out + (size_t)T_TOK * H_DIM;

  char* wsb = (char*)d_ws;
  size_t o = 0;
  auto nxt = [&](size_t bytes) -> void* {
    void* p = wsb + o;
    o += (bytes + 1023) & ~(size_t)1023;
    return p;
  };
  const size_t EXP_ELE = (size_t)T_TOK * K_TOP * I_DIM;  // 4M
  const size_t SH_ELE = (size_t)T_TOK * SI_DIM;          // 2M
  __bf16* x_bf = (__bf16*)nxt((size_t)T_TOK * H_DIM * 2);
  __bf16* gw_t = (__bf16*)nxt((size_t)E_NUM * I_DIM * H_DIM * 2);  // [E, I, H]
  __bf16* uw_t = (__bf16*)nxt((size_t)E_NUM * I_DIM * H_DIM * 2);
  __bf16* dw_t = (__bf16*)nxt((size_t)E_NUM * H_DIM * I_DIM * 2);  // [E, H, I]
  __bf16* sgw_t = (__bf16*)nxt((size_t)SI_DIM * H_DIM * 2);        // [SI, H]
  __bf16* suw_t = (__bf16*)nxt((size_t)SI_DIM * H_DIM * 2);
  __bf16* sdw_t = (__bf16*)nxt((size_t)H_DIM * SI_DIM * 2);  // [H, SI]
  __bf16* g_all = (__bf16*)nxt((EXP_ELE + SH_ELE) * 2);
  __bf16* u_all = (__bf16*)nxt((EXP_ELE + SH_ELE) * 2);
  __bf16* h_all = (__bf16*)nxt((EXP_ELE + SH_ELE) * 2);
  __bf16* eo = (__bf16*)nxt((size_t)T_TOK * K_TOP * H_DIM * 2);
  __bf16* so = (__bf16*)nxt((size_t)T_TOK * H_DIM * 2);
  float* gwt_f = (float*)nxt((size_t)E_NUM * H_DIM * 4);
  int* counts = (int*)nxt(64);
  int* offs = (int*)nxt(128);
  int* selE = (int*)nxt((size_t)T_TOK * K_TOP * 4);
  float* selW = (float*)nxt((size_t)T_TOK * K_TOP * 4);
  int* slot_of_tk = (int*)nxt((size_t)T_TOK * K_TOP * 4);
  int* tok_of_slot = (int*)nxt((size_t)T_TOK * K_TOP * 4);
  __bf16* g_buf = g_all;
  __bf16* gs_buf = g_all + EXP_ELE;
  __bf16* u_buf = u_all;
  __bf16* us_buf = u_all + EXP_ELE;
  __bf16* he = h_all;
  __bf16* hs = h_all + EXP_ELE;
  (void)ws_size;
  (void)in_sizes;
  (void)n_in;
  (void)out_size;

  dim3 tb(32, 8);
  transpose_all_kernel<<<13824, tb, 0, stream>>>(gate_w, up_w, down_w, sgw, suw, sdw, gw_t, uw_t,
                                                 dw_t, sgw_t, suw_t, sdw_t);
  transpose_gw_kernel<<<64, 256, 0, stream>>>(gate_weight, gwt_f);
  router_kernel<<<T_TOK, 256, 0, stream>>>(x, gwt_f, corr_bias, logits_out, x_bf, selE, selW);
  count_place_kernel<<<1, 1024, 0, stream>>>(selE, counts, offs, slot_of_tk, tok_of_slot);

  gemm_stage1<<<dim3(16, 16, E_NUM + 1), 256, 0, stream>>>(x_bf, tok_of_slot, counts, offs, gw_t,
                                                           uw_t, sgw_t, suw_t, g_buf, u_buf,
                                                           gs_buf, us_buf);
  silu_mul_kernel<<<(int)((EXP_ELE + SH_ELE) / 8 / 256), 256, 0, stream>>>(
      g_all, u_all, h_all, (long)(EXP_ELE + SH_ELE) / 8);
  gemm_stage2<<<dim3(8, 16, E_NUM + 1), 256, 0, stream>>>(he, hs, counts, offs, dw_t, sdw_t, eo,
                                                          so);

  combine_kernel<<<(T_TOK * H_DIM / 4) / 256, 256, 0, stream>>>(eo, so, slot_of_tk, selW, out);
}

// Round 7
// 178.623 us; speedup vs baseline: 1.0785x; 1.0785x over previous
//
#include <hip/hip_runtime.h>
#include <hip/hip_bf16.h>

#define T_TOK 2048
#define H_DIM 1024
#define E_NUM 16
#define I_DIM 512
#define K_TOP 4
#define SI_DIM 1024

typedef __bf16 bf16x8 __attribute__((ext_vector_type(8)));
typedef __bf16 bf16x4 __attribute__((ext_vector_type(4)));
typedef __bf16 bf16x2 __attribute__((ext_vector_type(2)));
typedef float f32x4 __attribute__((ext_vector_type(4)));

#define GL2L(g, l)                                                                       \
  __builtin_amdgcn_global_load_lds((const __attribute__((address_space(1))) void*)(g),   \
                                   (__attribute__((address_space(3))) void*)(l), 16, 0, 0)

// ---------------- transpose gate_weight [H,E] -> [E,H] (tiny) ----------------
__global__ void transpose_gw_kernel(const float* __restrict__ in, float* __restrict__ out) {
  int idx = blockIdx.x * 256 + threadIdx.x;  // 16384
  int e = idx >> 10, h = idx & 1023;
  out[idx] = in[h * E_NUM + e];
}

// -------- ALL weight transposes in one launch: fp32 [Z,R,C] -> bf16 [Z,C,R] --------
__global__ void transpose_all_kernel(const float* __restrict__ gate_w,
                                     const float* __restrict__ up_w,
                                     const float* __restrict__ down_w,
                                     const float* __restrict__ sgw, const float* __restrict__ suw,
                                     const float* __restrict__ sdw, __bf16* __restrict__ gw_t,
                                     __bf16* __restrict__ uw_t, __bf16* __restrict__ dw_t,
                                     __bf16* __restrict__ sgw_t, __bf16* __restrict__ suw_t,
                                     __bf16* __restrict__ sdw_t) {
  __shared__ float tile[64][33];
  int bid = blockIdx.x;
  const float* in;
  __bf16* out;
  int R, C, tile_id;
  if (bid < 8192) {
    bool g = bid < 4096;
    int b = bid & 4095;
    int z = b >> 8;
    tile_id = b & 255;
    R = H_DIM;
    C = I_DIM;
    size_t off = (size_t)z * R * C;
    in = (g ? gate_w : up_w) + off;
    out = (g ? gw_t : uw_t) + off;
  } else if (bid < 12288) {
    int b = bid - 8192;
    int z = b >> 8;
    tile_id = b & 255;
    R = I_DIM;
    C = H_DIM;
    size_t off = (size_t)z * R * C;
    in = down_w + off;
    out = dw_t + off;
  } else {
    int b = bid - 12288;
    int m = b >> 9;
    tile_id = b & 511;
    R = SI_DIM;
    C = H_DIM;
    in = m == 0 ? sgw : m == 1 ? suw : sdw;
    out = m == 0 ? sgw_t : m == 1 ? suw_t : sdw_t;
  }
  int xt = C >> 5;
  int cx = tile_id % xt, ry = tile_id / xt;
  int c0 = cx * 32, r0 = ry * 64;
  int tx = threadIdx.x, ty = threadIdx.y;  // 32 x 8
#pragma unroll
  for (int j = 0; j < 8; j++)
    tile[ty + 8 * j][tx] = in[(size_t)(r0 + ty + 8 * j) * C + c0 + tx];
  __syncthreads();
#pragma unroll
  for (int j = 0; j < 4; j++) {
    int cc = ty + 8 * j;
    bf16x2 v = {(__bf16)tile[tx * 2][cc], (__bf16)tile[tx * 2 + 1][cc]};
    *(bf16x2*)(out + (size_t)(c0 + cc) * R + r0 + tx * 2) = v;
  }
}

// ---------------- router: one block (4 waves) per token, fused x->bf16 cast ----------
__global__ __launch_bounds__(256) void router_kernel(
    const float* __restrict__ x, const float* __restrict__ gwt, const float* __restrict__ cbias,
    float* __restrict__ logits_out, __bf16* __restrict__ x_bf, int* __restrict__ selE,
    float* __restrict__ selW) {
  int t = blockIdx.x;
  int tid = threadIdx.x;
  int wid = tid >> 6, lane = tid & 63;
  int e = lane >> 2, cl = lane & 3;
  int c = wid * 4 + cl;  // 0..15
  const float* xr = x + (size_t)t * H_DIM + c * 64;
  const float* gr = gwt + (size_t)e * H_DIM + c * 64;
  float a0 = 0.f, a1 = 0.f, a2 = 0.f, a3 = 0.f;
#pragma unroll
  for (int j = 0; j < 16; j++) {
    float4 xv = *(const float4*)(xr + j * 4);
    float4 gv = *(const float4*)(gr + j * 4);
    if (e == 0) {
      bf16x4 o = {(__bf16)xv.x, (__bf16)xv.y, (__bf16)xv.z, (__bf16)xv.w};
      *(bf16x4*)(x_bf + (size_t)t * H_DIM + c * 64 + j * 4) = o;
    }
    a0 = fmaf(xv.x, gv.x, a0);
    a1 = fmaf(xv.y, gv.y, a1);
    a2 = fmaf(xv.z, gv.z, a2);
    a3 = fmaf(xv.w, gv.w, a3);
  }
  float a = (a0 + a1) + (a2 + a3);
  a += __shfl_xor(a, 1);
  a += __shfl_xor(a, 2);
  __shared__ float part[4][16];
  if (cl == 0) part[wid][e] = a;
  __syncthreads();
  if (wid != 0) return;
  float logit = -1e30f;
  if (lane < E_NUM)
    logit = (part[0][lane] + part[1][lane]) + (part[2][lane] + part[3][lane]);
  if (lane < E_NUM) logits_out[(size_t)t * E_NUM + lane] = logit;
  float m = logit;
#pragma unroll
  for (int mk = 8; mk >= 1; mk >>= 1) m = fmaxf(m, __shfl_xor(m, mk));
  float p = __expf(logit - m);
  float s = p;
#pragma unroll
  for (int mk = 8; mk >= 1; mk >>= 1) s += __shfl_xor(s, mk);
  p /= s;
  float score = (lane < E_NUM) ? p + cbias[lane] : -1e30f;
  int sel[K_TOP];
  float w[K_TOP];
#pragma unroll
  for (int k = 0; k < K_TOP; k++) {
    float bv = score;
    int bi = (lane < E_NUM) ? lane : 999;
#pragma unroll
    for (int mk = 1; mk <= 8; mk <<= 1) {
      float ov = __shfl_xor(bv, mk);
      int oi = __shfl_xor(bi, mk);
      if (ov > bv || (ov == bv && oi < bi)) {
        bv = ov;
        bi = oi;
      }
    }
    sel[k] = bi;
    w[k] = __shfl(p, bi);
    if (lane == bi) score = -1e30f;
  }
  if (lane == 0) {
    float wsum = fmaxf(w[0] + w[1] + w[2] + w[3], 1e-12f);
#pragma unroll
    for (int k = 0; k < K_TOP; k++) {
      selE[t * K_TOP + k] = sel[k];
      selW[t * K_TOP + k] = w[k] / wsum;
    }
  }
}

// ---------------- count + place, ONE block, ballot-based, zero global atomics ----------
__global__ __launch_bounds__(1024) void count_place_kernel(
    const int* __restrict__ selE, int* __restrict__ counts, int* __restrict__ offs,
    int* __restrict__ slot_of_tk, int* __restrict__ tok_of_slot) {
  int tid = threadIdx.x;
  int wv = tid >> 6, lane = tid & 63;
  unsigned long long lt = (1ULL << lane) - 1ULL;
  __shared__ int wcnt[16][16];
  __shared__ int wbase[16][16];
  __shared__ int glob[16];
  __shared__ int offsh[16];
  if (tid < 16) glob[tid] = 0;
  __syncthreads();
  int ex[8], rk[8];
#pragma unroll
  for (int r = 0; r < 8; r++) {
    int e = selE[r * 1024 + tid];
    ex[r] = e;
    int rank = 0;
#pragma unroll
    for (int q = 0; q < 16; q++) {
      unsigned long long b = __ballot(e == q);
      int c = __popcll(b & lt);
      if (e == q) rank = c;
      if (lane == q) wcnt[wv][q] = __popcll(b);
    }
    __syncthreads();
    if (wv == 0 && lane < 16) {
      int run = glob[lane];
#pragma unroll
      for (int w = 0; w < 16; w++) {
        wbase[w][lane] = run;
        run += wcnt[w][lane];
      }
      glob[lane] = run;
    }
    __syncthreads();
    rk[r] = rank + wbase[wv][e];
    __syncthreads();
  }
  if (wv == 0 && lane == 0) {
    int s = 0;
#pragma unroll
    for (int q = 0; q < 16; q++) {
      offsh[q] = s;
      s += glob[q];
    }
  }
  __syncthreads();
  if (tid < 16) {
    counts[tid] = glob[tid];
    offs[tid] = offsh[tid];
  }
#pragma unroll
  for (int r = 0; r < 8; r++) {
    int entry = r * 1024 + tid;
    int slot = offsh[ex[r]] + rk[r];
    slot_of_tk[entry] = slot;
    tok_of_slot[slot] = entry >> 2;
  }
}

// ---- 128x128 tile, BK=64, XOR-swizzled LDS, simple 2-barrier loop (R5, proven) ----
__device__ __forceinline__ void gemm_tile(const __bf16* __restrict__ A,
                                          const int* __restrict__ tokIdx, int rowOff, int M,
                                          int m0, int n0, int K, int ldC,
                                          const __bf16* __restrict__ Bp, __bf16* __restrict__ Cp,
                                          __bf16* Alds, __bf16* Blds) {
  int tid = threadIdx.x;
  int wave = tid >> 6, lane = tid & 63;
  int rsub = lane >> 3, chunk = lane & 7;
  int sch = (chunk ^ rsub) * 8;  // swizzled source offset (elems)
  size_t aB[4], bB[4];
#pragma unroll
  for (int j = 0; j < 4; j++) {
    int r = wave * 32 + j * 8 + rsub;
    int ar = m0 + r;
    ar = ar < M - 1 ? ar : M - 1;
    int grow = tokIdx ? tokIdx[rowOff + ar] : rowOff + ar;
    aB[j] = (size_t)grow * K + sch;
    bB[j] = (size_t)(n0 + r) * K + sch;
  }
  int wm = (wave >> 1) * 64, wn = (wave & 1) * 64;
  int rl = lane & 15, gq = lane >> 4;
  int xa = rl & 7;
  f32x4 acc[4][4] = {};
  for (int k0 = 0; k0 < K; k0 += 64) {
#pragma unroll
    for (int j = 0; j < 4; j++) {
      GL2L(A + aB[j] + k0, Alds + (wave * 32 + j * 8) * 64);
      GL2L(Bp + bB[j] + k0, Blds + (wave * 32 + j * 8) * 64);
    }
    __syncthreads();
#pragma unroll
    for (int s = 0; s < 2; s++) {
      int lc = ((s * 4 + gq) ^ xa) * 8;
      bf16x8 af[4], bfr[4];
#pragma unroll
      for (int m = 0; m < 4; m++) af[m] = *(const bf16x8*)&Alds[(wm + m * 16 + rl) * 64 + lc];
#pragma unroll
      for (int n = 0; n < 4; n++) bfr[n] = *(const bf16x8*)&Blds[(wn + n * 16 + rl) * 64 + lc];
#pragma unroll
      for (int m = 0; m < 4; m++)
#pragma unroll
        for (int n = 0; n < 4; n++)
          acc[m][n] =
              __builtin_amdgcn_mfma_f32_16x16x32_bf16(af[m], bfr[n], acc[m][n], 0, 0, 0);
    }
    __syncthreads();
  }
#pragma unroll
  for (int m = 0; m < 4; m++) {
#pragma unroll
    for (int b = 0; b < 4; b++) {
      int row = m0 + wm + m * 16 + gq * 4 + b;
      if (row < M) {
        size_t rb = (size_t)(rowOff + row) * ldC + n0 + wn + rl;
#pragma unroll
        for (int n = 0; n < 4; n++) Cp[rb + n * 16] = (__bf16)acc[m][n][b];
      }
    }
  }
}

// stage 1 FUSED: h = silu(x@Wg) * (x@Wu) in one block. A staged once, two B tiles,
// silu*mul in the epilogue -> writes only h (g/u never touch HBM; silu kernel gone).
__global__ __launch_bounds__(256, 2) void gemm_stage1(
    const __bf16* __restrict__ x_bf, const int* __restrict__ tok_of_slot,
    const int* __restrict__ counts, const int* __restrict__ offs, const __bf16* __restrict__ gw_t,
    const __bf16* __restrict__ uw_t, const __bf16* __restrict__ sgw_t,
    const __bf16* __restrict__ suw_t, __bf16* __restrict__ he, __bf16* __restrict__ hs) {
  __shared__ __align__(16) __bf16 Alds[8192];
  __shared__ __align__(16) __bf16 Bgl[8192];
  __shared__ __align__(16) __bf16 Bul[8192];
  int z = blockIdx.z, bx = blockIdx.x, m0 = blockIdx.y * 128;
  const __bf16 *Bg, *Bu;
  __bf16* Cp;
  const int* tokIdx;
  int rowOff, M, ldC, n0;
  if (z < E_NUM) {
    if (bx >= 4) return;
    M = counts[z];
    if (m0 >= M) return;
    tokIdx = tok_of_slot;
    rowOff = offs[z];
    Bg = gw_t + (size_t)z * I_DIM * H_DIM;
    Bu = uw_t + (size_t)z * I_DIM * H_DIM;
    Cp = he;
    ldC = I_DIM;
    n0 = bx * 128;
  } else {
    tokIdx = nullptr;
    rowOff = 0;
    M = T_TOK;
    Bg = sgw_t;
    Bu = suw_t;
    Cp = hs;
    ldC = SI_DIM;
    n0 = bx * 128;
  }
  int tid = threadIdx.x;
  int wave = tid >> 6, lane = tid & 63;
  int rsub = lane >> 3, chunk = lane & 7;
  int sch = (chunk ^ rsub) * 8;
  size_t aB[4], bB[4];
#pragma unroll
  for (int j = 0; j < 4; j++) {
    int r = wave * 32 + j * 8 + rsub;
    int ar = m0 + r;
    ar = ar < M - 1 ? ar : M - 1;
    int grow = tokIdx ? tokIdx[rowOff + ar] : rowOff + ar;
    aB[j] = (size_t)grow * H_DIM + sch;
    bB[j] = (size_t)(n0 + r) * H_DIM + sch;
  }
  int wm = (wave >> 1) * 64, wn = (wave & 1) * 64;
  int rl = lane & 15, gq = lane >> 4;
  int xa = rl & 7;
  f32x4 accg[4][4] = {}, accu[4][4] = {};
  for (int k0 = 0; k0 < H_DIM; k0 += 64) {
#pragma unroll
    for (int j = 0; j < 4; j++) {
      int ld = (wave * 32 + j * 8) * 64;
      GL2L(x_bf + aB[j] + k0, Alds + ld);
      GL2L(Bg + bB[j] + k0, Bgl + ld);
      GL2L(Bu + bB[j] + k0, Bul + ld);
    }
    __syncthreads();
#pragma unroll
    for (int s = 0; s < 2; s++) {
      int lc = ((s * 4 + gq) ^ xa) * 8;
      bf16x8 af[4], bg[4], bu[4];
#pragma unroll
      for (int m = 0; m < 4; m++) af[m] = *(const bf16x8*)&Alds[(wm + m * 16 + rl) * 64 + lc];
#pragma unroll
      for (int n = 0; n < 4; n++) {
        bg[n] = *(const bf16x8*)&Bgl[(wn + n * 16 + rl) * 64 + lc];
        bu[n] = *(const bf16x8*)&Bul[(wn + n * 16 + rl) * 64 + lc];
      }
#pragma unroll
      for (int m = 0; m < 4; m++)
#pragma unroll
        for (int n = 0; n < 4; n++) {
          accg[m][n] =
              __builtin_amdgcn_mfma_f32_16x16x32_bf16(af[m], bg[n], accg[m][n], 0, 0, 0);
          accu[m][n] =
              __builtin_amdgcn_mfma_f32_16x16x32_bf16(af[m], bu[n], accu[m][n], 0, 0, 0);
        }
    }
    __syncthreads();
  }
#pragma unroll
  for (int m = 0; m < 4; m++) {
#pragma unroll
    for (int b = 0; b < 4; b++) {
      int row = m0 + wm + m * 16 + gq * 4 + b;
      if (row < M) {
        size_t rb = (size_t)(rowOff + row) * ldC + n0 + wn + rl;
#pragma unroll
        for (int n = 0; n < 4; n++) {
          float g = accg[m][n][b];
          float u = accu[m][n][b];
          float h = g / (1.f + __expf(-g)) * u;
          Cp[rb + n * 16] = (__bf16)h;
        }
      }
    }
  }
}

// stage 2: expert down (z<16) + shared down (z==16)
__global__ __launch_bounds__(256, 2) void gemm_stage2(
    const __bf16* __restrict__ he, const __bf16* __restrict__ hs, const int* __restrict__ counts,
    const int* __restrict__ offs, const __bf16* __restrict__ dw_t,
    const __bf16* __restrict__ sdw_t, __bf16* __restrict__ eo, __bf16* __restrict__ so) {
  __shared__ __align__(16) __bf16 Alds[8192];
  __shared__ __align__(16) __bf16 Blds[8192];
  int z = blockIdx.z, bx = blockIdx.x, m0 = blockIdx.y * 128;
  if (z < E_NUM) {
    int M = counts[z];
    if (m0 >= M) return;
    gemm_tile(he, nullptr, offs[z], M, m0, bx * 128, I_DIM, H_DIM,
              dw_t + (size_t)z * H_DIM * I_DIM, eo, Alds, Blds);
  } else {
    gemm_tile(hs, nullptr, 0, T_TOK, m0, bx * 128, SI_DIM, H_DIM, sdw_t, so, Alds, Blds);
  }
}

// ---------------- combine: out = shared + sum_k w_k * eo[slot_k] ----------------
__global__ void combine_kernel(const __bf16* __restrict__ eo, const __bf16* __restrict__ so,
                               const int* __restrict__ slot_of_tk, const float* __restrict__ selW,
                               float* __restrict__ out) {
  int idx = blockIdx.x * blockDim.x + threadIdx.x;
  int t = idx >> 8;
  int h4 = (idx & 255) * 4;
  if (t >= T_TOK) return;
  bf16x4 sv = *(const bf16x4*)(so + (size_t)t * H_DIM + h4);
  float a0 = (float)sv[0], a1 = (float)sv[1], a2 = (float)sv[2], a3 = (float)sv[3];
#pragma unroll
  for (int k = 0; k < K_TOP; k++) {
    int slot = slot_of_tk[t * K_TOP + k];
    float w = selW[t * K_TOP + k];
    bf16x4 ev = *(const bf16x4*)(eo + (size_t)slot * H_DIM + h4);
    a0 += w * (float)ev[0];
    a1 += w * (float)ev[1];
    a2 += w * (float)ev[2];
    a3 += w * (float)ev[3];
  }
  *(float4*)(out + (size_t)t * H_DIM + h4) = make_float4(a0, a1, a2, a3);
}

extern "C" void kernel_launch(void* const* d_in, const int* in_sizes, int n_in, void* d_out,
                              int out_size, void* d_ws, size_t ws_size, hipStream_t stream) {
  const float* x = (const float*)d_in[0];
  const float* gate_weight = (const float*)d_in[1];
  const float* corr_bias = (const float*)d_in[2];
  const float* gate_w = (const float*)d_in[3];
  const float* up_w = (const float*)d_in[4];
  const float* down_w = (const float*)d_in[5];
  const float* sgw = (const float*)d_in[6];
  const float* suw = (const float*)d_in[7];
  const float* sdw = (const float*)d_in[8];
  float* out = (float*)d_out;
  float* logits_out = out + (size_t)T_TOK * H_DIM;

  char* wsb = (char*)d_ws;
  size_t o = 0;
  auto nxt = [&](size_t bytes) -> void* {
    void* p = wsb + o;
    o += (bytes + 1023) & ~(size_t)1023;
    return p;
  };
  const size_t EXP_ELE = (size_t)T_TOK * K_TOP * I_DIM;  // 4M
  const size_t SH_ELE = (size_t)T_TOK * SI_DIM;          // 2M
  __bf16* x_bf = (__bf16*)nxt((size_t)T_TOK * H_DIM * 2);
  __bf16* gw_t = (__bf16*)nxt((size_t)E_NUM * I_DIM * H_DIM * 2);  // [E, I, H]
  __bf16* uw_t = (__bf16*)nxt((size_t)E_NUM * I_DIM * H_DIM * 2);
  __bf16* dw_t = (__bf16*)nxt((size_t)E_NUM * H_DIM * I_DIM * 2);  // [E, H, I]
  __bf16* sgw_t = (__bf16*)nxt((size_t)SI_DIM * H_DIM * 2);        // [SI, H]
  __bf16* suw_t = (__bf16*)nxt((size_t)SI_DIM * H_DIM * 2);
  __bf16* sdw_t = (__bf16*)nxt((size_t)H_DIM * SI_DIM * 2);  // [H, SI]
  __bf16* h_all = (__bf16*)nxt((EXP_ELE + SH_ELE) * 2);
  __bf16* eo = (__bf16*)nxt((size_t)T_TOK * K_TOP * H_DIM * 2);
  __bf16* so = (__bf16*)nxt((size_t)T_TOK * H_DIM * 2);
  float* gwt_f = (float*)nxt((size_t)E_NUM * H_DIM * 4);
  int* counts = (int*)nxt(64);
  int* offs = (int*)nxt(128);
  int* selE = (int*)nxt((size_t)T_TOK * K_TOP * 4);
  float* selW = (float*)nxt((size_t)T_TOK * K_TOP * 4);
  int* slot_of_tk = (int*)nxt((size_t)T_TOK * K_TOP * 4);
  int* tok_of_slot = (int*)nxt((size_t)T_TOK * K_TOP * 4);
  __bf16* he = h_all;
  __bf16* hs = h_all + EXP_ELE;
  (void)ws_size;
  (void)in_sizes;
  (void)n_in;
  (void)out_size;

  dim3 tb(32, 8);
  transpose_all_kernel<<<13824, tb, 0, stream>>>(gate_w, up_w, down_w, sgw, suw, sdw, gw_t, uw_t,
                                                 dw_t, sgw_t, suw_t, sdw_t);
  transpose_gw_kernel<<<64, 256, 0, stream>>>(gate_weight, gwt_f);
  router_kernel<<<T_TOK, 256, 0, stream>>>(x, gwt_f, corr_bias, logits_out, x_bf, selE, selW);
  count_place_kernel<<<1, 1024, 0, stream>>>(selE, counts, offs, slot_of_tk, tok_of_slot);

  gemm_stage1<<<dim3(8, 16, E_NUM + 1), 256, 0, stream>>>(x_bf, tok_of_slot, counts, offs, gw_t,
                                                          uw_t, sgw_t, suw_t, he, hs);
  gemm_stage2<<<dim3(8, 16, E_NUM + 1), 256, 0, stream>>>(he, hs, counts, offs, dw_t, sdw_t, eo,
                                                          so);

  combine_kernel<<<(T_TOK * H_DIM / 4) / 256, 256, 0, stream>>>(eo, so, slot_of_tk, selW, out);
}

// Round 8
// 166.218 us; speedup vs baseline: 1.1590x; 1.0746x over previous
//
#include <hip/hip_runtime.h>
#include <hip/hip_bf16.h>

#define T_TOK 2048
#define H_DIM 1024
#define E_NUM 16
#define I_DIM 512
#define K_TOP 4
#define SI_DIM 1024

typedef __bf16 bf16x8 __attribute__((ext_vector_type(8)));
typedef __bf16 bf16x4 __attribute__((ext_vector_type(4)));
typedef __bf16 bf16x2 __attribute__((ext_vector_type(2)));
typedef float f32x4 __attribute__((ext_vector_type(4)));

#define GL2L(g, l)                                                                       \
  __builtin_amdgcn_global_load_lds((const __attribute__((address_space(1))) void*)(g),   \
                                   (__attribute__((address_space(3))) void*)(l), 16, 0, 0)

// ---------------- transpose gate_weight [H,E] -> [E,H] (tiny) ----------------
__global__ void transpose_gw_kernel(const float* __restrict__ in, float* __restrict__ out) {
  int idx = blockIdx.x * 256 + threadIdx.x;  // 16384
  int e = idx >> 10, h = idx & 1023;
  out[idx] = in[h * E_NUM + e];
}

// -------- ALL weight transposes in one launch: fp32 [Z,R,C] -> bf16 [Z,C,R] --------
__global__ void transpose_all_kernel(const float* __restrict__ gate_w,
                                     const float* __restrict__ up_w,
                                     const float* __restrict__ down_w,
                                     const float* __restrict__ sgw, const float* __restrict__ suw,
                                     const float* __restrict__ sdw, __bf16* __restrict__ gw_t,
                                     __bf16* __restrict__ uw_t, __bf16* __restrict__ dw_t,
                                     __bf16* __restrict__ sgw_t, __bf16* __restrict__ suw_t,
                                     __bf16* __restrict__ sdw_t) {
  __shared__ float tile[64][33];
  int bid = blockIdx.x;
  const float* in;
  __bf16* out;
  int R, C, tile_id;
  if (bid < 8192) {
    bool g = bid < 4096;
    int b = bid & 4095;
    int z = b >> 8;
    tile_id = b & 255;
    R = H_DIM;
    C = I_DIM;
    size_t off = (size_t)z * R * C;
    in = (g ? gate_w : up_w) + off;
    out = (g ? gw_t : uw_t) + off;
  } else if (bid < 12288) {
    int b = bid - 8192;
    int z = b >> 8;
    tile_id = b & 255;
    R = I_DIM;
    C = H_DIM;
    size_t off = (size_t)z * R * C;
    in = down_w + off;
    out = dw_t + off;
  } else {
    int b = bid - 12288;
    int m = b >> 9;
    tile_id = b & 511;
    R = SI_DIM;
    C = H_DIM;
    in = m == 0 ? sgw : m == 1 ? suw : sdw;
    out = m == 0 ? sgw_t : m == 1 ? suw_t : sdw_t;
  }
  int xt = C >> 5;
  int cx = tile_id % xt, ry = tile_id / xt;
  int c0 = cx * 32, r0 = ry * 64;
  int tx = threadIdx.x, ty = threadIdx.y;  // 32 x 8
#pragma unroll
  for (int j = 0; j < 8; j++)
    tile[ty + 8 * j][tx] = in[(size_t)(r0 + ty + 8 * j) * C + c0 + tx];
  __syncthreads();
#pragma unroll
  for (int j = 0; j < 4; j++) {
    int cc = ty + 8 * j;
    bf16x2 v = {(__bf16)tile[tx * 2][cc], (__bf16)tile[tx * 2 + 1][cc]};
    *(bf16x2*)(out + (size_t)(c0 + cc) * R + r0 + tx * 2) = v;
  }
}

// ---------------- router: one block (4 waves) per token, fused x->bf16 cast ----------
__global__ __launch_bounds__(256) void router_kernel(
    const float* __restrict__ x, const float* __restrict__ gwt, const float* __restrict__ cbias,
    float* __restrict__ logits_out, __bf16* __restrict__ x_bf, int* __restrict__ selE,
    float* __restrict__ selW) {
  int t = blockIdx.x;
  int tid = threadIdx.x;
  int wid = tid >> 6, lane = tid & 63;
  int e = lane >> 2, cl = lane & 3;
  int c = wid * 4 + cl;  // 0..15
  const float* xr = x + (size_t)t * H_DIM + c * 64;
  const float* gr = gwt + (size_t)e * H_DIM + c * 64;
  float a0 = 0.f, a1 = 0.f, a2 = 0.f, a3 = 0.f;
#pragma unroll
  for (int j = 0; j < 16; j++) {
    float4 xv = *(const float4*)(xr + j * 4);
    float4 gv = *(const float4*)(gr + j * 4);
    if (e == 0) {
      bf16x4 o = {(__bf16)xv.x, (__bf16)xv.y, (__bf16)xv.z, (__bf16)xv.w};
      *(bf16x4*)(x_bf + (size_t)t * H_DIM + c * 64 + j * 4) = o;
    }
    a0 = fmaf(xv.x, gv.x, a0);
    a1 = fmaf(xv.y, gv.y, a1);
    a2 = fmaf(xv.z, gv.z, a2);
    a3 = fmaf(xv.w, gv.w, a3);
  }
  float a = (a0 + a1) + (a2 + a3);
  a += __shfl_xor(a, 1);
  a += __shfl_xor(a, 2);
  __shared__ float part[4][16];
  if (cl == 0) part[wid][e] = a;
  __syncthreads();
  if (wid != 0) return;
  float logit = -1e30f;
  if (lane < E_NUM)
    logit = (part[0][lane] + part[1][lane]) + (part[2][lane] + part[3][lane]);
  if (lane < E_NUM) logits_out[(size_t)t * E_NUM + lane] = logit;
  float m = logit;
#pragma unroll
  for (int mk = 8; mk >= 1; mk >>= 1) m = fmaxf(m, __shfl_xor(m, mk));
  float p = __expf(logit - m);
  float s = p;
#pragma unroll
  for (int mk = 8; mk >= 1; mk >>= 1) s += __shfl_xor(s, mk);
  p /= s;
  float score = (lane < E_NUM) ? p + cbias[lane] : -1e30f;
  int sel[K_TOP];
  float w[K_TOP];
#pragma unroll
  for (int k = 0; k < K_TOP; k++) {
    float bv = score;
    int bi = (lane < E_NUM) ? lane : 999;
#pragma unroll
    for (int mk = 1; mk <= 8; mk <<= 1) {
      float ov = __shfl_xor(bv, mk);
      int oi = __shfl_xor(bi, mk);
      if (ov > bv || (ov == bv && oi < bi)) {
        bv = ov;
        bi = oi;
      }
    }
    sel[k] = bi;
    w[k] = __shfl(p, bi);
    if (lane == bi) score = -1e30f;
  }
  if (lane == 0) {
    float wsum = fmaxf(w[0] + w[1] + w[2] + w[3], 1e-12f);
#pragma unroll
    for (int k = 0; k < K_TOP; k++) {
      selE[t * K_TOP + k] = sel[k];
      selW[t * K_TOP + k] = w[k] / wsum;
    }
  }
}

// ---------------- count + place, ONE block, ballot-based, zero global atomics ----------
__global__ __launch_bounds__(1024) void count_place_kernel(
    const int* __restrict__ selE, int* __restrict__ counts, int* __restrict__ offs,
    int* __restrict__ slot_of_tk, int* __restrict__ tok_of_slot) {
  int tid = threadIdx.x;
  int wv = tid >> 6, lane = tid & 63;
  unsigned long long lt = (1ULL << lane) - 1ULL;
  __shared__ int wcnt[16][16];
  __shared__ int wbase[16][16];
  __shared__ int glob[16];
  __shared__ int offsh[16];
  if (tid < 16) glob[tid] = 0;
  __syncthreads();
  int ex[8], rk[8];
#pragma unroll
  for (int r = 0; r < 8; r++) {
    int e = selE[r * 1024 + tid];
    ex[r] = e;
    int rank = 0;
#pragma unroll
    for (int q = 0; q < 16; q++) {
      unsigned long long b = __ballot(e == q);
      int c = __popcll(b & lt);
      if (e == q) rank = c;
      if (lane == q) wcnt[wv][q] = __popcll(b);
    }
    __syncthreads();
    if (wv == 0 && lane < 16) {
      int run = glob[lane];
#pragma unroll
      for (int w = 0; w < 16; w++) {
        wbase[w][lane] = run;
        run += wcnt[w][lane];
      }
      glob[lane] = run;
    }
    __syncthreads();
    rk[r] = rank + wbase[wv][e];
    __syncthreads();
  }
  if (wv == 0 && lane == 0) {
    int s = 0;
#pragma unroll
    for (int q = 0; q < 16; q++) {
      offsh[q] = s;
      s += glob[q];
    }
  }
  __syncthreads();
  if (tid < 16) {
    counts[tid] = glob[tid];
    offs[tid] = offsh[tid];
  }
#pragma unroll
  for (int r = 0; r < 8; r++) {
    int entry = r * 1024 + tid;
    int slot = offsh[ex[r]] + rk[r];
    slot_of_tk[entry] = slot;
    tok_of_slot[slot] = entry >> 2;
  }
}

// stage 1 FUSED, 128x64 tile: h = silu(x@Wg)*(x@Wu). A staged once, Bg+Bu 64-row tiles,
// silu*mul epilogue. 2x2 wave grid: wave owns 64x32. XOR-swizzle source+read (rule #21).
__global__ __launch_bounds__(256, 3) void gemm_stage1(
    const __bf16* __restrict__ x_bf, const int* __restrict__ tok_of_slot,
    const int* __restrict__ counts, const int* __restrict__ offs, const __bf16* __restrict__ gw_t,
    const __bf16* __restrict__ uw_t, const __bf16* __restrict__ sgw_t,
    const __bf16* __restrict__ suw_t, __bf16* __restrict__ he, __bf16* __restrict__ hs) {
  __shared__ __align__(16) __bf16 Alds[128 * 64];  // 16KB
  __shared__ __align__(16) __bf16 Bgl[64 * 64];    // 8KB
  __shared__ __align__(16) __bf16 Bul[64 * 64];    // 8KB
  int z = blockIdx.z, bx = blockIdx.x, m0 = blockIdx.y * 128;
  const __bf16 *Bg, *Bu;
  __bf16* Cp;
  const int* tokIdx;
  int rowOff, M, ldC, n0;
  if (z < E_NUM) {
    if (bx >= 8) return;
    M = counts[z];
    if (m0 >= M) return;
    tokIdx = tok_of_slot;
    rowOff = offs[z];
    Bg = gw_t + (size_t)z * I_DIM * H_DIM;
    Bu = uw_t + (size_t)z * I_DIM * H_DIM;
    Cp = he;
    ldC = I_DIM;
    n0 = bx * 64;
  } else {
    tokIdx = nullptr;
    rowOff = 0;
    M = T_TOK;
    Bg = sgw_t;
    Bu = suw_t;
    Cp = hs;
    ldC = SI_DIM;
    n0 = bx * 64;
  }
  int tid = threadIdx.x;
  int wave = tid >> 6, lane = tid & 63;
  int rsub = lane >> 3, chunk = lane & 7;
  int sch = (chunk ^ rsub) * 8;
  size_t aB[4], bB[2];
#pragma unroll
  for (int j = 0; j < 4; j++) {
    int r = wave * 32 + j * 8 + rsub;
    int ar = m0 + r;
    ar = ar < M - 1 ? ar : M - 1;
    int grow = tokIdx ? tokIdx[rowOff + ar] : rowOff + ar;
    aB[j] = (size_t)grow * H_DIM + sch;
  }
#pragma unroll
  for (int j = 0; j < 2; j++) {
    int r = wave * 16 + j * 8 + rsub;
    bB[j] = (size_t)(n0 + r) * H_DIM + sch;
  }
  int wm = (wave >> 1) * 64, wn = (wave & 1) * 32;
  int rl = lane & 15, gq = lane >> 4;
  int xa = rl & 7;
  f32x4 accg[4][2] = {}, accu[4][2] = {};
  for (int k0 = 0; k0 < H_DIM; k0 += 64) {
#pragma unroll
    for (int j = 0; j < 4; j++) GL2L(x_bf + aB[j] + k0, Alds + (wave * 32 + j * 8) * 64);
#pragma unroll
    for (int j = 0; j < 2; j++) {
      int ld = (wave * 16 + j * 8) * 64;
      GL2L(Bg + bB[j] + k0, Bgl + ld);
      GL2L(Bu + bB[j] + k0, Bul + ld);
    }
    __syncthreads();
#pragma unroll
    for (int s = 0; s < 2; s++) {
      int lc = ((s * 4 + gq) ^ xa) * 8;
      bf16x8 af[4], bg[2], bu[2];
#pragma unroll
      for (int m = 0; m < 4; m++) af[m] = *(const bf16x8*)&Alds[(wm + m * 16 + rl) * 64 + lc];
#pragma unroll
      for (int n = 0; n < 2; n++) {
        bg[n] = *(const bf16x8*)&Bgl[(wn + n * 16 + rl) * 64 + lc];
        bu[n] = *(const bf16x8*)&Bul[(wn + n * 16 + rl) * 64 + lc];
      }
#pragma unroll
      for (int m = 0; m < 4; m++)
#pragma unroll
        for (int n = 0; n < 2; n++) {
          accg[m][n] =
              __builtin_amdgcn_mfma_f32_16x16x32_bf16(af[m], bg[n], accg[m][n], 0, 0, 0);
          accu[m][n] =
              __builtin_amdgcn_mfma_f32_16x16x32_bf16(af[m], bu[n], accu[m][n], 0, 0, 0);
        }
    }
    __syncthreads();
  }
#pragma unroll
  for (int m = 0; m < 4; m++) {
#pragma unroll
    for (int b = 0; b < 4; b++) {
      int row = m0 + wm + m * 16 + gq * 4 + b;
      if (row < M) {
        size_t rb = (size_t)(rowOff + row) * ldC + n0 + wn + rl;
#pragma unroll
        for (int n = 0; n < 2; n++) {
          float g = accg[m][n][b];
          float u = accu[m][n][b];
          float h = g / (1.f + __expf(-g)) * u;
          Cp[rb + n * 16] = (__bf16)h;
        }
      }
    }
  }
}

// stage 2, 128x64 tile: expert down (z<16) + shared down (z==16)
__global__ __launch_bounds__(256, 4) void gemm_stage2(
    const __bf16* __restrict__ he, const __bf16* __restrict__ hs, const int* __restrict__ counts,
    const int* __restrict__ offs, const __bf16* __restrict__ dw_t,
    const __bf16* __restrict__ sdw_t, __bf16* __restrict__ eo, __bf16* __restrict__ so) {
  __shared__ __align__(16) __bf16 Alds[128 * 64];  // 16KB
  __shared__ __align__(16) __bf16 Blds[64 * 64];   // 8KB
  int z = blockIdx.z, bx = blockIdx.x, m0 = blockIdx.y * 128;
  const __bf16 *A, *Bp;
  __bf16* Cp;
  int rowOff, M, K;
  if (z < E_NUM) {
    M = counts[z];
    if (m0 >= M) return;
    A = he;
    rowOff = offs[z];
    K = I_DIM;
    Bp = dw_t + (size_t)z * H_DIM * I_DIM;
    Cp = eo;
  } else {
    A = hs;
    rowOff = 0;
    M = T_TOK;
    K = SI_DIM;
    Bp = sdw_t;
    Cp = so;
  }
  int n0 = bx * 64;
  int tid = threadIdx.x;
  int wave = tid >> 6, lane = tid & 63;
  int rsub = lane >> 3, chunk = lane & 7;
  int sch = (chunk ^ rsub) * 8;
  size_t aB[4], bB[2];
#pragma unroll
  for (int j = 0; j < 4; j++) {
    int r = wave * 32 + j * 8 + rsub;
    int ar = m0 + r;
    ar = ar < M - 1 ? ar : M - 1;
    aB[j] = (size_t)(rowOff + ar) * K + sch;
  }
#pragma unroll
  for (int j = 0; j < 2; j++) {
    int r = wave * 16 + j * 8 + rsub;
    bB[j] = (size_t)(n0 + r) * K + sch;
  }
  int wm = (wave >> 1) * 64, wn = (wave & 1) * 32;
  int rl = lane & 15, gq = lane >> 4;
  int xa = rl & 7;
  f32x4 acc[4][2] = {};
  for (int k0 = 0; k0 < K; k0 += 64) {
#pragma unroll
    for (int j = 0; j < 4; j++) GL2L(A + aB[j] + k0, Alds + (wave * 32 + j * 8) * 64);
#pragma unroll
    for (int j = 0; j < 2; j++) GL2L(Bp + bB[j] + k0, Blds + (wave * 16 + j * 8) * 64);
    __syncthreads();
#pragma unroll
    for (int s = 0; s < 2; s++) {
      int lc = ((s * 4 + gq) ^ xa) * 8;
      bf16x8 af[4], bfr[2];
#pragma unroll
      for (int m = 0; m < 4; m++) af[m] = *(const bf16x8*)&Alds[(wm + m * 16 + rl) * 64 + lc];
#pragma unroll
      for (int n = 0; n < 2; n++) bfr[n] = *(const bf16x8*)&Blds[(wn + n * 16 + rl) * 64 + lc];
#pragma unroll
      for (int m = 0; m < 4; m++)
#pragma unroll
        for (int n = 0; n < 2; n++)
          acc[m][n] =
              __builtin_amdgcn_mfma_f32_16x16x32_bf16(af[m], bfr[n], acc[m][n], 0, 0, 0);
    }
    __syncthreads();
  }
#pragma unroll
  for (int m = 0; m < 4; m++) {
#pragma unroll
    for (int b = 0; b < 4; b++) {
      int row = m0 + wm + m * 16 + gq * 4 + b;
      if (row < M) {
        size_t rb = (size_t)(rowOff + row) * H_DIM + n0 + wn + rl;
#pragma unroll
        for (int n = 0; n < 2; n++) Cp[rb + n * 16] = (__bf16)acc[m][n][b];
      }
    }
  }
}

// ---------------- combine: out = shared + sum_k w_k * eo[slot_k] ----------------
__global__ void combine_kernel(const __bf16* __restrict__ eo, const __bf16* __restrict__ so,
                               const int* __restrict__ slot_of_tk, const float* __restrict__ selW,
                               float* __restrict__ out) {
  int idx = blockIdx.x * blockDim.x + threadIdx.x;
  int t = idx >> 8;
  int h4 = (idx & 255) * 4;
  if (t >= T_TOK) return;
  bf16x4 sv = *(const bf16x4*)(so + (size_t)t * H_DIM + h4);
  float a0 = (float)sv[0], a1 = (float)sv[1], a2 = (float)sv[2], a3 = (float)sv[3];
#pragma unroll
  for (int k = 0; k < K_TOP; k++) {
    int slot = slot_of_tk[t * K_TOP + k];
    float w = selW[t * K_TOP + k];
    bf16x4 ev = *(const bf16x4*)(eo + (size_t)slot * H_DIM + h4);
    a0 += w * (float)ev[0];
    a1 += w * (float)ev[1];
    a2 += w * (float)ev[2];
    a3 += w * (float)ev[3];
  }
  *(float4*)(out + (size_t)t * H_DIM + h4) = make_float4(a0, a1, a2, a3);
}

extern "C" void kernel_launch(void* const* d_in, const int* in_sizes, int n_in, void* d_out,
                              int out_size, void* d_ws, size_t ws_size, hipStream_t stream) {
  const float* x = (const float*)d_in[0];
  const float* gate_weight = (const float*)d_in[1];
  const float* corr_bias = (const float*)d_in[2];
  const float* gate_w = (const float*)d_in[3];
  const float* up_w = (const float*)d_in[4];
  const float* down_w = (const float*)d_in[5];
  const float* sgw = (const float*)d_in[6];
  const float* suw = (const float*)d_in[7];
  const float* sdw = (const float*)d_in[8];
  float* out = (float*)d_out;
  float* logits_out = out + (size_t)T_TOK * H_DIM;

  char* wsb = (char*)d_ws;
  size_t o = 0;
  auto nxt = [&](size_t bytes) -> void* {
    void* p = wsb + o;
    o += (bytes + 1023) & ~(size_t)1023;
    return p;
  };
  const size_t EXP_ELE = (size_t)T_TOK * K_TOP * I_DIM;  // 4M
  const size_t SH_ELE = (size_t)T_TOK * SI_DIM;          // 2M
  __bf16* x_bf = (__bf16*)nxt((size_t)T_TOK * H_DIM * 2);
  __bf16* gw_t = (__bf16*)nxt((size_t)E_NUM * I_DIM * H_DIM * 2);  // [E, I, H]
  __bf16* uw_t = (__bf16*)nxt((size_t)E_NUM * I_DIM * H_DIM * 2);
  __bf16* dw_t = (__bf16*)nxt((size_t)E_NUM * H_DIM * I_DIM * 2);  // [E, H, I]
  __bf16* sgw_t = (__bf16*)nxt((size_t)SI_DIM * H_DIM * 2);        // [SI, H]
  __bf16* suw_t = (__bf16*)nxt((size_t)SI_DIM * H_DIM * 2);
  __bf16* sdw_t = (__bf16*)nxt((size_t)H_DIM * SI_DIM * 2);  // [H, SI]
  __bf16* h_all = (__bf16*)nxt((EXP_ELE + SH_ELE) * 2);
  __bf16* eo = (__bf16*)nxt((size_t)T_TOK * K_TOP * H_DIM * 2);
  __bf16* so = (__bf16*)nxt((size_t)T_TOK * H_DIM * 2);
  float* gwt_f = (float*)nxt((size_t)E_NUM * H_DIM * 4);
  int* counts = (int*)nxt(64);
  int* offs = (int*)nxt(128);
  int* selE = (int*)nxt((size_t)T_TOK * K_TOP * 4);
  float* selW = (float*)nxt((size_t)T_TOK * K_TOP * 4);
  int* slot_of_tk = (int*)nxt((size_t)T_TOK * K_TOP * 4);
  int* tok_of_slot = (int*)nxt((size_t)T_TOK * K_TOP * 4);
  __bf16* he = h_all;
  __bf16* hs = h_all + EXP_ELE;
  (void)ws_size;
  (void)in_sizes;
  (void)n_in;
  (void)out_size;

  dim3 tb(32, 8);
  transpose_all_kernel<<<13824, tb, 0, stream>>>(gate_w, up_w, down_w, sgw, suw, sdw, gw_t, uw_t,
                                                 dw_t, sgw_t, suw_t, sdw_t);
  transpose_gw_kernel<<<64, 256, 0, stream>>>(gate_weight, gwt_f);
  router_kernel<<<T_TOK, 256, 0, stream>>>(x, gwt_f, corr_bias, logits_out, x_bf, selE, selW);
  count_place_kernel<<<1, 1024, 0, stream>>>(selE, counts, offs, slot_of_tk, tok_of_slot);

  gemm_stage1<<<dim3(16, 16, E_NUM + 1), 256, 0, stream>>>(x_bf, tok_of_slot, counts, offs, gw_t,
                                                           uw_t, sgw_t, suw_t, he, hs);
  gemm_stage2<<<dim3(16, 16, E_NUM + 1), 256, 0, stream>>>(he, hs, counts, offs, dw_t, sdw_t, eo,
                                                           so);

  combine_kernel<<<(T_TOK * H_DIM / 4) / 256, 256, 0, stream>>>(eo, so, slot_of_tk, selW, out);
}

// Round 9
// 162.908 us; speedup vs baseline: 1.1825x; 1.0203x over previous
//
#include <hip/hip_runtime.h>
#include <hip/hip_bf16.h>

#define T_TOK 2048
#define H_DIM 1024
#define E_NUM 16
#define I_DIM 512
#define K_TOP 4
#define SI_DIM 1024

typedef __bf16 bf16x8 __attribute__((ext_vector_type(8)));
typedef __bf16 bf16x4 __attribute__((ext_vector_type(4)));
typedef __bf16 bf16x2 __attribute__((ext_vector_type(2)));
typedef float f32x4 __attribute__((ext_vector_type(4)));

#define GL2L(g, l)                                                                       \
  __builtin_amdgcn_global_load_lds((const __attribute__((address_space(1))) void*)(g),   \
                                   (__attribute__((address_space(3))) void*)(l), 16, 0, 0)
#define BAR() __builtin_amdgcn_s_barrier()

// ---------------- transpose gate_weight [H,E] -> [E,H] (tiny) ----------------
__global__ void transpose_gw_kernel(const float* __restrict__ in, float* __restrict__ out) {
  int idx = blockIdx.x * 256 + threadIdx.x;  // 16384
  int e = idx >> 10, h = idx & 1023;
  out[idx] = in[h * E_NUM + e];
}

// -------- ALL weight transposes in one launch: fp32 [Z,R,C] -> bf16 [Z,C,R] --------
__global__ void transpose_all_kernel(const float* __restrict__ gate_w,
                                     const float* __restrict__ up_w,
                                     const float* __restrict__ down_w,
                                     const float* __restrict__ sgw, const float* __restrict__ suw,
                                     const float* __restrict__ sdw, __bf16* __restrict__ gw_t,
                                     __bf16* __restrict__ uw_t, __bf16* __restrict__ dw_t,
                                     __bf16* __restrict__ sgw_t, __bf16* __restrict__ suw_t,
                                     __bf16* __restrict__ sdw_t) {
  __shared__ float tile[64][33];
  int bid = blockIdx.x;
  const float* in;
  __bf16* out;
  int R, C, tile_id;
  if (bid < 8192) {
    bool g = bid < 4096;
    int b = bid & 4095;
    int z = b >> 8;
    tile_id = b & 255;
    R = H_DIM;
    C = I_DIM;
    size_t off = (size_t)z * R * C;
    in = (g ? gate_w : up_w) + off;
    out = (g ? gw_t : uw_t) + off;
  } else if (bid < 12288) {
    int b = bid - 8192;
    int z = b >> 8;
    tile_id = b & 255;
    R = I_DIM;
    C = H_DIM;
    size_t off = (size_t)z * R * C;
    in = down_w + off;
    out = dw_t + off;
  } else {
    int b = bid - 12288;
    int m = b >> 9;
    tile_id = b & 511;
    R = SI_DIM;
    C = H_DIM;
    in = m == 0 ? sgw : m == 1 ? suw : sdw;
    out = m == 0 ? sgw_t : m == 1 ? suw_t : sdw_t;
  }
  int xt = C >> 5;
  int cx = tile_id % xt, ry = tile_id / xt;
  int c0 = cx * 32, r0 = ry * 64;
  int tx = threadIdx.x, ty = threadIdx.y;  // 32 x 8
#pragma unroll
  for (int j = 0; j < 8; j++)
    tile[ty + 8 * j][tx] = in[(size_t)(r0 + ty + 8 * j) * C + c0 + tx];
  __syncthreads();
#pragma unroll
  for (int j = 0; j < 4; j++) {
    int cc = ty + 8 * j;
    bf16x2 v = {(__bf16)tile[tx * 2][cc], (__bf16)tile[tx * 2 + 1][cc]};
    *(bf16x2*)(out + (size_t)(c0 + cc) * R + r0 + tx * 2) = v;
  }
}

// ---------------- router: one block (4 waves) per token, fused x->bf16 cast ----------
__global__ __launch_bounds__(256) void router_kernel(
    const float* __restrict__ x, const float* __restrict__ gwt, const float* __restrict__ cbias,
    float* __restrict__ logits_out, __bf16* __restrict__ x_bf, int* __restrict__ selE,
    float* __restrict__ selW) {
  int t = blockIdx.x;
  int tid = threadIdx.x;
  int wid = tid >> 6, lane = tid & 63;
  int e = lane >> 2, cl = lane & 3;
  int c = wid * 4 + cl;  // 0..15
  const float* xr = x + (size_t)t * H_DIM + c * 64;
  const float* gr = gwt + (size_t)e * H_DIM + c * 64;
  float a0 = 0.f, a1 = 0.f, a2 = 0.f, a3 = 0.f;
#pragma unroll
  for (int j = 0; j < 16; j++) {
    float4 xv = *(const float4*)(xr + j * 4);
    float4 gv = *(const float4*)(gr + j * 4);
    if (e == 0) {
      bf16x4 o = {(__bf16)xv.x, (__bf16)xv.y, (__bf16)xv.z, (__bf16)xv.w};
      *(bf16x4*)(x_bf + (size_t)t * H_DIM + c * 64 + j * 4) = o;
    }
    a0 = fmaf(xv.x, gv.x, a0);
    a1 = fmaf(xv.y, gv.y, a1);
    a2 = fmaf(xv.z, gv.z, a2);
    a3 = fmaf(xv.w, gv.w, a3);
  }
  float a = (a0 + a1) + (a2 + a3);
  a += __shfl_xor(a, 1);
  a += __shfl_xor(a, 2);
  __shared__ float part[4][16];
  if (cl == 0) part[wid][e] = a;
  __syncthreads();
  if (wid != 0) return;
  float logit = -1e30f;
  if (lane < E_NUM)
    logit = (part[0][lane] + part[1][lane]) + (part[2][lane] + part[3][lane]);
  if (lane < E_NUM) logits_out[(size_t)t * E_NUM + lane] = logit;
  float m = logit;
#pragma unroll
  for (int mk = 8; mk >= 1; mk >>= 1) m = fmaxf(m, __shfl_xor(m, mk));
  float p = __expf(logit - m);
  float s = p;
#pragma unroll
  for (int mk = 8; mk >= 1; mk >>= 1) s += __shfl_xor(s, mk);
  p /= s;
  float score = (lane < E_NUM) ? p + cbias[lane] : -1e30f;
  int sel[K_TOP];
  float w[K_TOP];
#pragma unroll
  for (int k = 0; k < K_TOP; k++) {
    float bv = score;
    int bi = (lane < E_NUM) ? lane : 999;
#pragma unroll
    for (int mk = 1; mk <= 8; mk <<= 1) {
      float ov = __shfl_xor(bv, mk);
      int oi = __shfl_xor(bi, mk);
      if (ov > bv || (ov == bv && oi < bi)) {
        bv = ov;
        bi = oi;
      }
    }
    sel[k] = bi;
    w[k] = __shfl(p, bi);
    if (lane == bi) score = -1e30f;
  }
  if (lane == 0) {
    float wsum = fmaxf(w[0] + w[1] + w[2] + w[3], 1e-12f);
#pragma unroll
    for (int k = 0; k < K_TOP; k++) {
      selE[t * K_TOP + k] = sel[k];
      selW[t * K_TOP + k] = w[k] / wsum;
    }
  }
}

// ---------------- count + place, ONE block, ballot-based, zero global atomics ----------
__global__ __launch_bounds__(1024) void count_place_kernel(
    const int* __restrict__ selE, int* __restrict__ counts, int* __restrict__ offs,
    int* __restrict__ slot_of_tk, int* __restrict__ tok_of_slot) {
  int tid = threadIdx.x;
  int wv = tid >> 6, lane = tid & 63;
  unsigned long long lt = (1ULL << lane) - 1ULL;
  __shared__ int wcnt[16][16];
  __shared__ int wbase[16][16];
  __shared__ int glob[16];
  __shared__ int offsh[16];
  if (tid < 16) glob[tid] = 0;
  __syncthreads();
  int ex[8], rk[8];
#pragma unroll
  for (int r = 0; r < 8; r++) {
    int e = selE[r * 1024 + tid];
    ex[r] = e;
    int rank = 0;
#pragma unroll
    for (int q = 0; q < 16; q++) {
      unsigned long long b = __ballot(e == q);
      int c = __popcll(b & lt);
      if (e == q) rank = c;
      if (lane == q) wcnt[wv][q] = __popcll(b);
    }
    __syncthreads();
    if (wv == 0 && lane < 16) {
      int run = glob[lane];
#pragma unroll
      for (int w = 0; w < 16; w++) {
        wbase[w][lane] = run;
        run += wcnt[w][lane];
      }
      glob[lane] = run;
    }
    __syncthreads();
    rk[r] = rank + wbase[wv][e];
    __syncthreads();
  }
  if (wv == 0 && lane == 0) {
    int s = 0;
#pragma unroll
    for (int q = 0; q < 16; q++) {
      offsh[q] = s;
      s += glob[q];
    }
  }
  __syncthreads();
  if (tid < 16) {
    counts[tid] = glob[tid];
    offs[tid] = offsh[tid];
  }
#pragma unroll
  for (int r = 0; r < 8; r++) {
    int entry = r * 1024 + tid;
    int slot = offsh[ex[r]] + rk[r];
    slot_of_tk[entry] = slot;
    tok_of_slot[slot] = entry >> 2;
  }
}

// stage 1 FUSED, 128x64 tile, counted-vmcnt pipeline (T4, m201 pattern):
// B (cold HBM) double-buffered, prefetched 1 step ahead; A (L2-warm) single-buffered.
// Per iter: STAGE_B(t+1); vmcnt(4) [drains A(t),B(t), leaves B(t+1) in flight];
// raw barrier; ds_read+MFMA; raw barrier; STAGE_A(t+1). No __syncthreads in the loop.
__global__ __launch_bounds__(256, 3) void gemm_stage1(
    const __bf16* __restrict__ x_bf, const int* __restrict__ tok_of_slot,
    const int* __restrict__ counts, const int* __restrict__ offs, const __bf16* __restrict__ gw_t,
    const __bf16* __restrict__ uw_t, const __bf16* __restrict__ sgw_t,
    const __bf16* __restrict__ suw_t, __bf16* __restrict__ he, __bf16* __restrict__ hs) {
  __shared__ __align__(16) __bf16 Alds[128 * 64];      // 16KB
  __shared__ __align__(16) __bf16 Bgl[2 * 64 * 64];    // 16KB (dbuf)
  __shared__ __align__(16) __bf16 Bul[2 * 64 * 64];    // 16KB (dbuf)
  int z = blockIdx.z, bx = blockIdx.x, m0 = blockIdx.y * 128;
  const __bf16 *Bg, *Bu;
  __bf16* Cp;
  const int* tokIdx;
  int rowOff, M, ldC, n0;
  if (z < E_NUM) {
    if (bx >= 8) return;
    M = counts[z];
    if (m0 >= M) return;
    tokIdx = tok_of_slot;
    rowOff = offs[z];
    Bg = gw_t + (size_t)z * I_DIM * H_DIM;
    Bu = uw_t + (size_t)z * I_DIM * H_DIM;
    Cp = he;
    ldC = I_DIM;
    n0 = bx * 64;
  } else {
    tokIdx = nullptr;
    rowOff = 0;
    M = T_TOK;
    Bg = sgw_t;
    Bu = suw_t;
    Cp = hs;
    ldC = SI_DIM;
    n0 = bx * 64;
  }
  int tid = threadIdx.x;
  int wave = tid >> 6, lane = tid & 63;
  int rsub = lane >> 3, chunk = lane & 7;
  int sch = (chunk ^ rsub) * 8;
  size_t aB[4], bB[2];
#pragma unroll
  for (int j = 0; j < 4; j++) {
    int r = wave * 32 + j * 8 + rsub;
    int ar = m0 + r;
    ar = ar < M - 1 ? ar : M - 1;
    int grow = tokIdx ? tokIdx[rowOff + ar] : rowOff + ar;
    aB[j] = (size_t)grow * H_DIM + sch;
  }
#pragma unroll
  for (int j = 0; j < 2; j++) {
    int r = wave * 16 + j * 8 + rsub;
    bB[j] = (size_t)(n0 + r) * H_DIM + sch;
  }
  int wm = (wave >> 1) * 64, wn = (wave & 1) * 32;
  int rl = lane & 15, gq = lane >> 4;
  int xa = rl & 7;

  auto STAGE_A = [&](int k0) {
#pragma unroll
    for (int j = 0; j < 4; j++) GL2L(x_bf + aB[j] + k0, Alds + (wave * 32 + j * 8) * 64);
  };
  auto STAGE_B = [&](int k0, int buf) {
#pragma unroll
    for (int j = 0; j < 2; j++) {
      int ld = buf * 4096 + (wave * 16 + j * 8) * 64;
      GL2L(Bg + bB[j] + k0, Bgl + ld);
      GL2L(Bu + bB[j] + k0, Bul + ld);
    }
  };

  f32x4 accg[4][2] = {}, accu[4][2] = {};
  const int NT = H_DIM / 64;  // 16
  STAGE_A(0);
  STAGE_B(0, 0);
  int buf = 0;
  for (int t = 0; t < NT; ++t) {
    if (t + 1 < NT) {
      STAGE_B((t + 1) << 6, buf ^ 1);
      asm volatile("s_waitcnt vmcnt(4)" ::: "memory");
    } else {
      asm volatile("s_waitcnt vmcnt(0)" ::: "memory");
    }
    BAR();
    const __bf16* Bgr = Bgl + buf * 4096;
    const __bf16* Bur = Bul + buf * 4096;
#pragma unroll
    for (int s = 0; s < 2; s++) {
      int lc = ((s * 4 + gq) ^ xa) * 8;
      bf16x8 af[4], bg[2], bu[2];
#pragma unroll
      for (int m = 0; m < 4; m++) af[m] = *(const bf16x8*)&Alds[(wm + m * 16 + rl) * 64 + lc];
#pragma unroll
      for (int n = 0; n < 2; n++) {
        bg[n] = *(const bf16x8*)&Bgr[(wn + n * 16 + rl) * 64 + lc];
        bu[n] = *(const bf16x8*)&Bur[(wn + n * 16 + rl) * 64 + lc];
      }
#pragma unroll
      for (int m = 0; m < 4; m++)
#pragma unroll
        for (int n = 0; n < 2; n++) {
          accg[m][n] =
              __builtin_amdgcn_mfma_f32_16x16x32_bf16(af[m], bg[n], accg[m][n], 0, 0, 0);
          accu[m][n] =
              __builtin_amdgcn_mfma_f32_16x16x32_bf16(af[m], bu[n], accu[m][n], 0, 0, 0);
        }
    }
    BAR();
    if (t + 1 < NT) STAGE_A((t + 1) << 6);
    buf ^= 1;
  }
#pragma unroll
  for (int m = 0; m < 4; m++) {
#pragma unroll
    for (int b = 0; b < 4; b++) {
      int row = m0 + wm + m * 16 + gq * 4 + b;
      if (row < M) {
        size_t rb = (size_t)(rowOff + row) * ldC + n0 + wn + rl;
#pragma unroll
        for (int n = 0; n < 2; n++) {
          float g = accg[m][n][b];
          float u = accu[m][n][b];
          float h = g / (1.f + __expf(-g)) * u;
          Cp[rb + n * 16] = (__bf16)h;
        }
      }
    }
  }
}

// stage 2, 128x64 tile, same counted-vmcnt pipeline (B loads/iter = 2 -> vmcnt(2))
__global__ __launch_bounds__(256, 4) void gemm_stage2(
    const __bf16* __restrict__ he, const __bf16* __restrict__ hs, const int* __restrict__ counts,
    const int* __restrict__ offs, const __bf16* __restrict__ dw_t,
    const __bf16* __restrict__ sdw_t, __bf16* __restrict__ eo, __bf16* __restrict__ so) {
  __shared__ __align__(16) __bf16 Alds[128 * 64];    // 16KB
  __shared__ __align__(16) __bf16 Blds[2 * 64 * 64]; // 16KB (dbuf)
  int z = blockIdx.z, bx = blockIdx.x, m0 = blockIdx.y * 128;
  const __bf16 *A, *Bp;
  __bf16* Cp;
  int rowOff, M, K;
  if (z < E_NUM) {
    M = counts[z];
    if (m0 >= M) return;
    A = he;
    rowOff = offs[z];
    K = I_DIM;
    Bp = dw_t + (size_t)z * H_DIM * I_DIM;
    Cp = eo;
  } else {
    A = hs;
    rowOff = 0;
    M = T_TOK;
    K = SI_DIM;
    Bp = sdw_t;
    Cp = so;
  }
  int n0 = bx * 64;
  int tid = threadIdx.x;
  int wave = tid >> 6, lane = tid & 63;
  int rsub = lane >> 3, chunk = lane & 7;
  int sch = (chunk ^ rsub) * 8;
  size_t aB[4], bB[2];
#pragma unroll
  for (int j = 0; j < 4; j++) {
    int r = wave * 32 + j * 8 + rsub;
    int ar = m0 + r;
    ar = ar < M - 1 ? ar : M - 1;
    aB[j] = (size_t)(rowOff + ar) * K + sch;
  }
#pragma unroll
  for (int j = 0; j < 2; j++) {
    int r = wave * 16 + j * 8 + rsub;
    bB[j] = (size_t)(n0 + r) * K + sch;
  }
  int wm = (wave >> 1) * 64, wn = (wave & 1) * 32;
  int rl = lane & 15, gq = lane >> 4;
  int xa = rl & 7;

  auto STAGE_A = [&](int k0) {
#pragma unroll
    for (int j = 0; j < 4; j++) GL2L(A + aB[j] + k0, Alds + (wave * 32 + j * 8) * 64);
  };
  auto STAGE_B = [&](int k0, int b) {
#pragma unroll
    for (int j = 0; j < 2; j++)
      GL2L(Bp + bB[j] + k0, Blds + b * 4096 + (wave * 16 + j * 8) * 64);
  };

  f32x4 acc[4][2] = {};
  const int NT = K >> 6;
  STAGE_A(0);
  STAGE_B(0, 0);
  int buf = 0;
  for (int t = 0; t < NT; ++t) {
    if (t + 1 < NT) {
      STAGE_B((t + 1) << 6, buf ^ 1);
      asm volatile("s_waitcnt vmcnt(2)" ::: "memory");
    } else {
      asm volatile("s_waitcnt vmcnt(0)" ::: "memory");
    }
    BAR();
    const __bf16* Br = Blds + buf * 4096;
#pragma unroll
    for (int s = 0; s < 2; s++) {
      int lc = ((s * 4 + gq) ^ xa) * 8;
      bf16x8 af[4], bfr[2];
#pragma unroll
      for (int m = 0; m < 4; m++) af[m] = *(const bf16x8*)&Alds[(wm + m * 16 + rl) * 64 + lc];
#pragma unroll
      for (int n = 0; n < 2; n++) bfr[n] = *(const bf16x8*)&Br[(wn + n * 16 + rl) * 64 + lc];
#pragma unroll
      for (int m = 0; m < 4; m++)
#pragma unroll
        for (int n = 0; n < 2; n++)
          acc[m][n] =
              __builtin_amdgcn_mfma_f32_16x16x32_bf16(af[m], bfr[n], acc[m][n], 0, 0, 0);
    }
    BAR();
    if (t + 1 < NT) STAGE_A((t + 1) << 6);
    buf ^= 1;
  }
#pragma unroll
  for (int m = 0; m < 4; m++) {
#pragma unroll
    for (int b = 0; b < 4; b++) {
      int row = m0 + wm + m * 16 + gq * 4 + b;
      if (row < M) {
        size_t rb = (size_t)(rowOff + row) * H_DIM + n0 + wn + rl;
#pragma unroll
        for (int n = 0; n < 2; n++) Cp[rb + n * 16] = (__bf16)acc[m][n][b];
      }
    }
  }
}

// ---------------- combine: out = shared + sum_k w_k * eo[slot_k] ----------------
__global__ void combine_kernel(const __bf16* __restrict__ eo, const __bf16* __restrict__ so,
                               const int* __restrict__ slot_of_tk, const float* __restrict__ selW,
                               float* __restrict__ out) {
  int idx = blockIdx.x * blockDim.x + threadIdx.x;
  int t = idx >> 8;
  int h4 = (idx & 255) * 4;
  if (t >= T_TOK) return;
  bf16x4 sv = *(const bf16x4*)(so + (size_t)t * H_DIM + h4);
  float a0 = (float)sv[0], a1 = (float)sv[1], a2 = (float)sv[2], a3 = (float)sv[3];
#pragma unroll
  for (int k = 0; k < K_TOP; k++) {
    int slot = slot_of_tk[t * K_TOP + k];
    float w = selW[t * K_TOP + k];
    bf16x4 ev = *(const bf16x4*)(eo + (size_t)slot * H_DIM + h4);
    a0 += w * (float)ev[0];
    a1 += w * (float)ev[1];
    a2 += w * (float)ev[2];
    a3 += w * (float)ev[3];
  }
  *(float4*)(out + (size_t)t * H_DIM + h4) = make_float4(a0, a1, a2, a3);
}

extern "C" void kernel_launch(void* const* d_in, const int* in_sizes, int n_in, void* d_out,
                              int out_size, void* d_ws, size_t ws_size, hipStream_t stream) {
  const float* x = (const float*)d_in[0];
  const float* gate_weight = (const float*)d_in[1];
  const float* corr_bias = (const float*)d_in[2];
  const float* gate_w = (const float*)d_in[3];
  const float* up_w = (const float*)d_in[4];
  const float* down_w = (const float*)d_in[5];
  const float* sgw = (const float*)d_in[6];
  const float* suw = (const float*)d_in[7];
  const float* sdw = (const float*)d_in[8];
  float* out = (float*)d_out;
  float* logits_out = out + (size_t)T_TOK * H_DIM;

  char* wsb = (char*)d_ws;
  size_t o = 0;
  auto nxt = [&](size_t bytes) -> void* {
    void* p = wsb + o;
    o += (bytes + 1023) & ~(size_t)1023;
    return p;
  };
  const size_t EXP_ELE = (size_t)T_TOK * K_TOP * I_DIM;  // 4M
  const size_t SH_ELE = (size_t)T_TOK * SI_DIM;          // 2M
  __bf16* x_bf = (__bf16*)nxt((size_t)T_TOK * H_DIM * 2);
  __bf16* gw_t = (__bf16*)nxt((size_t)E_NUM * I_DIM * H_DIM * 2);  // [E, I, H]
  __bf16* uw_t = (__bf16*)nxt((size_t)E_NUM * I_DIM * H_DIM * 2);
  __bf16* dw_t = (__bf16*)nxt((size_t)E_NUM * H_DIM * I_DIM * 2);  // [E, H, I]
  __bf16* sgw_t = (__bf16*)nxt((size_t)SI_DIM * H_DIM * 2);        // [SI, H]
  __bf16* suw_t = (__bf16*)nxt((size_t)SI_DIM * H_DIM * 2);
  __bf16* sdw_t = (__bf16*)nxt((size_t)H_DIM * SI_DIM * 2);  // [H, SI]
  __bf16* h_all = (__bf16*)nxt((EXP_ELE + SH_ELE) * 2);
  __bf16* eo = (__bf16*)nxt((size_t)T_TOK * K_TOP * H_DIM * 2);
  __bf16* so = (__bf16*)nxt((size_t)T_TOK * H_DIM * 2);
  float* gwt_f = (float*)nxt((size_t)E_NUM * H_DIM * 4);
  int* counts = (int*)nxt(64);
  int* offs = (int*)nxt(128);
  int* selE = (int*)nxt((size_t)T_TOK * K_TOP * 4);
  float* selW = (float*)nxt((size_t)T_TOK * K_TOP * 4);
  int* slot_of_tk = (int*)nxt((size_t)T_TOK * K_TOP * 4);
  int* tok_of_slot = (int*)nxt((size_t)T_TOK * K_TOP * 4);
  __bf16* he = h_all;
  __bf16* hs = h_all + EXP_ELE;
  (void)ws_size;
  (void)in_sizes;
  (void)n_in;
  (void)out_size;

  dim3 tb(32, 8);
  transpose_all_kernel<<<13824, tb, 0, stream>>>(gate_w, up_w, down_w, sgw, suw, sdw, gw_t, uw_t,
                                                 dw_t, sgw_t, suw_t, sdw_t);
  transpose_gw_kernel<<<64, 256, 0, stream>>>(gate_weight, gwt_f);
  router_kernel<<<T_TOK, 256, 0, stream>>>(x, gwt_f, corr_bias, logits_out, x_bf, selE, selW);
  count_place_kernel<<<1, 1024, 0, stream>>>(selE, counts, offs, slot_of_tk, tok_of_slot);

  gemm_stage1<<<dim3(16, 16, E_NUM + 1), 256, 0, stream>>>(x_bf, tok_of_slot, counts, offs, gw_t,
                                                           uw_t, sgw_t, suw_t, he, hs);
  gemm_stage2<<<dim3(16, 16, E_NUM + 1), 256, 0, stream>>>(he, hs, counts, offs, dw_t, sdw_t, eo,
                                                           so);

  combine_kernel<<<(T_TOK * H_DIM / 4) / 256, 256, 0, stream>>>(eo, so, slot_of_tk, selW, out);
}